// Round 4
// baseline (980.649 us; speedup 1.0000x reference)
//
#include <hip/hip_runtime.h>

typedef unsigned short u16;
typedef __attribute__((ext_vector_type(8))) short short8;
typedef __attribute__((ext_vector_type(4))) float f32x4;

#define NB 32768

__device__ __forceinline__ u16 f2bf(float x){
  unsigned int u = __float_as_uint(x);
  u += 0x7fffu + ((u >> 16) & 1u);
  return (u16)(u >> 16);
}
__device__ __forceinline__ float bf2f(short h){
  return __uint_as_float(((unsigned int)(u16)h) << 16);
}
__device__ __forceinline__ short8 pack8(float4 a, float4 b){
  short8 p;
  p[0]=(short)f2bf(a.x); p[1]=(short)f2bf(a.y); p[2]=(short)f2bf(a.z); p[3]=(short)f2bf(a.w);
  p[4]=(short)f2bf(b.x); p[5]=(short)f2bf(b.y); p[6]=(short)f2bf(b.z); p[7]=(short)f2bf(b.w);
  return p;
}

// ---------------- K0: weight convert/transpose to bf16 [N][K] ----------------
__global__ __launch_bounds__(256) void k0_conv(
    const float* __restrict__ Wenc, const float* __restrict__ Wsenc,
    const float* __restrict__ Wk, const float* __restrict__ Wsel, const float* __restrict__ Wv,
    const float* __restrict__ Wc1, const float* __restrict__ Wc2,
    u16* __restrict__ WencB, u16* __restrict__ WsencB,
    u16* __restrict__ WkB, u16* __restrict__ WvB, u16* __restrict__ WselB,
    u16* __restrict__ Wc1B, u16* __restrict__ Wc2B)
{
  int idx = blockIdx.x * 256 + threadIdx.x;
  if (idx < 307200){                       // WencB[a][n<128][k<160] = Wenc[a][k][n]
    int a = idx / 20480, r = idx % 20480, n = r / 160, k = r % 160;
    WencB[idx] = f2bf(Wenc[a*20480 + k*128 + n]);
  } else if (idx < 552960){                // WsencB[a][n][k] 128x128
    int i = idx - 307200; int a = i / 16384, r = i % 16384, n = r / 128, k = r % 128;
    WsencB[i] = f2bf(Wsenc[a*16384 + k*128 + n]);
  } else if (idx < 569344){                // WkB[c=nh*32+d][k<128] = Wk[nh][k][d]
    int i = idx - 552960; int c = i / 128, k = i % 128;
    WkB[i] = f2bf(Wk[(c>>5)*4096 + k*32 + (c&31)]);
  } else if (idx < 585728){
    int i = idx - 569344; int c = i / 128, k = i % 128;
    WvB[i] = f2bf(Wv[(c>>5)*4096 + k*32 + (c&31)]);
  } else if (idx < 602112){
    int i = idx - 585728; int c = i / 128, k = i % 128;
    WselB[i] = f2bf(Wsel[(c>>5)*4096 + k*32 + (c&31)]);
  } else if (idx < 1093632){               // Wc1B[a][n<128][k<256] = Wc1[a][k][n]
    int i = idx - 602112; int a = i / 32768, r = i % 32768, n = r / 256, k = r % 256;
    Wc1B[i] = f2bf(Wc1[a*32768 + k*128 + n]);
  } else if (idx < 1155072){               // Wc2B[a][n<32][k<128] = Wc2[a][k][n]
    int i = idx - 1093632; int a = i / 4096, r = i % 4096, n = r / 128, k = r % 128;
    Wc2B[i] = f2bf(Wc2[a*4096 + k*32 + n]);
  }
}

// ---------------- fused main kernel ----------------
// Block = 16 batch rows x 15 agents; 960 threads = 15 waves; wave w owns agent w.
// LDS regions:
//   R1 @0      : 61440  SA (transient, own-wave bounce) -> V_all [240][256B swz]
//   R2 @61440  : 61440  S -> SE (transient bounce) -> attn -> hidden  [240][256B swz]
//   P1 @122880 : 15360  actions -> K_h [240][64B];  P1..P2 also out f32 bounce at end
//   P2 @138240 : 15360  sel_h [240][64B]
#define R1o 0
#define R2o 61440
#define P1o 122880
#define P2o 138240
#define LDS_TOT 153600

__device__ __forceinline__ short8 ldA(const char* lds, int off, int row, int slot){
  return *(const short8*)(lds + off + row*256 + ((slot ^ (row & 7)) << 4));
}
__device__ __forceinline__ void stSwz(char* lds, int off, int row, int col, u16 v){
  *(u16*)(lds + off + row*256 + ((((col>>3) ^ (row&7))) << 4) + ((col&7) << 1)) = v;
}

#define MFMA(a8,b8,c) __builtin_amdgcn_mfma_f32_16x16x32_bf16(a8, b8, c, 0, 0, 0)

__global__ __launch_bounds__(960, 4) void k_fused(
    const float* __restrict__ states, const float* __restrict__ actions,
    const float* __restrict__ benc, const float* __restrict__ bsenc, const float* __restrict__ bvp,
    const float* __restrict__ bc1, const float* __restrict__ bc2,
    const u16* __restrict__ WencB, const u16* __restrict__ WsencB,
    const u16* __restrict__ WkB, const u16* __restrict__ WvB, const u16* __restrict__ WselB,
    const u16* __restrict__ Wc1B, const u16* __restrict__ Wc2B,
    float* __restrict__ outp)
{
  extern __shared__ __align__(16) char lds[];
  const int b0 = blockIdx.x * 16;
  const int lane = threadIdx.x & 63, w = threadIdx.x >> 6;   // w = agent, 0..14
  const int l15 = lane & 15, l4 = lane >> 4;

  // ---- stage S -> R2, actions -> P1 (all wave-local: no barrier) ----
  #pragma unroll
  for (int it = 0; it < 4; ++it){
    int r = it*4 + l4;
    const float* sp = states + ((size_t)w*NB + b0 + r)*128 + l15*8;
    float4 v0 = *(const float4*)sp, v1 = *(const float4*)(sp + 4);
    int row = w*16 + r;
    *(short8*)(lds + R2o + row*256 + ((l15 ^ (row&7)) << 4)) = pack8(v0, v1);
  }
  {
    int r = lane >> 2, ch = lane & 3;
    const float* ap = actions + ((size_t)w*NB + b0 + r)*32 + ch*8;
    float4 v0 = *(const float4*)ap, v1 = *(const float4*)(ap + 4);
    int row = w*16 + r;
    *(short8*)(lds + P1o + row*64 + ((ch ^ (row&3)) << 4)) = pack8(v0, v1);
  }

  // ---- A-fragments of S and act (own rows; same-wave RAW is HW-ordered) ----
  short8 s8[4];
  #pragma unroll
  for (int ks = 0; ks < 4; ++ks) s8[ks] = ldA(lds, R2o, w*16 + l15, ks*4 + l4);
  short8 aa;
  { int row = w*16 + l15; aa = *(const short8*)(lds + P1o + row*64 + ((l4 ^ (row&3)) << 4)); }

  // ---- SA = lrelu([S|act] @ Wenc + benc) -> R1 (own rows) ----
  {
    const u16* We = WencB + (size_t)w*20480;
    #pragma unroll
    for (int uu = 0; uu < 2; ++uu)
    #pragma unroll
    for (int fn = 0; fn < 4; ++fn){
      int col = uu*64 + fn*16 + l15;
      const u16* Wn = We + (size_t)col*160;
      f32x4 a = (f32x4)0.f;
      #pragma unroll
      for (int ks = 0; ks < 4; ++ks) a = MFMA(s8[ks], *(const short8*)(Wn + ks*32 + l4*8), a);
      a = MFMA(aa, *(const short8*)(Wn + 128 + l4*8), a);
      float bb = benc[w*128 + col];
      #pragma unroll
      for (int q = 0; q < 4; ++q){
        int row = w*16 + l4*4 + q;
        float v = a[q] + bb; v = v > 0.f ? v : 0.01f*v;
        stSwz(lds, R1o, row, col, f2bf(v));
      }
    }
  }
  // ---- SE = lrelu(S @ Wsenc + bsenc) -> R2 (overwrites S; s8 already in regs) ----
  {
    const u16* Ws = WsencB + (size_t)w*16384;
    #pragma unroll
    for (int uu = 0; uu < 2; ++uu)
    #pragma unroll
    for (int fn = 0; fn < 4; ++fn){
      int col = uu*64 + fn*16 + l15;
      const u16* Wn = Ws + (size_t)col*128;
      f32x4 a = (f32x4)0.f;
      #pragma unroll
      for (int ks = 0; ks < 4; ++ks) a = MFMA(s8[ks], *(const short8*)(Wn + ks*32 + l4*8), a);
      float bb = bsenc[w*128 + col];
      #pragma unroll
      for (int q = 0; q < 4; ++q){
        int row = w*16 + l4*4 + q;
        float v = a[q] + bb; v = v > 0.f ? v : 0.01f*v;
        stSwz(lds, R2o, row, col, f2bf(v));
      }
    }
  }

  // ---- read back SA/SE as persistent A-fragments (own rows, same-wave) ----
  short8 saA[4], seA[4];
  #pragma unroll
  for (int ks = 0; ks < 4; ++ks){
    saA[ks] = ldA(lds, R1o, w*16 + l15, ks*4 + l4);
    seA[ks] = ldA(lds, R2o, w*16 + l15, ks*4 + l4);
  }

  // ---- V_all = lrelu(SA @ Wv + bv) -> R1 (overwrites SA; saA in regs) ----
  #pragma unroll
  for (int uu = 0; uu < 2; ++uu)
  #pragma unroll
  for (int fn = 0; fn < 4; ++fn){
    int col = uu*64 + fn*16 + l15;          // col = h*32 + d
    const u16* Wn = WvB + (size_t)col*128;
    f32x4 a = (f32x4)0.f;
    #pragma unroll
    for (int ks = 0; ks < 4; ++ks) a = MFMA(saA[ks], *(const short8*)(Wn + ks*32 + l4*8), a);
    float bb = bvp[col];
    #pragma unroll
    for (int q = 0; q < 4; ++q){
      int row = w*16 + l4*4 + q;
      float v = a[q] + bb; v = v > 0.f ? v : 0.01f*v;
      stSwz(lds, R1o, row, col, f2bf(v));
    }
  }
  // ---- K_0 -> P1, sel_0 -> P2 ----
  #pragma unroll
  for (int fn = 0; fn < 2; ++fn){
    int col = fn*16 + l15;
    f32x4 a = (f32x4)0.f, s = (f32x4)0.f;
    const u16* Wkn = WkB   + (size_t)col*128;
    const u16* Wsn = WselB + (size_t)col*128;
    #pragma unroll
    for (int ks = 0; ks < 4; ++ks){
      a = MFMA(saA[ks], *(const short8*)(Wkn + ks*32 + l4*8), a);
      s = MFMA(seA[ks], *(const short8*)(Wsn + ks*32 + l4*8), s);
    }
    #pragma unroll
    for (int q = 0; q < 4; ++q){
      int row = w*16 + l4*4 + q;
      *(u16*)(lds + P1o + row*64 + col*2) = f2bf(a[q]);
      *(u16*)(lds + P2o + row*64 + col*2) = f2bf(s[q]);
    }
  }
  __syncthreads();                                         // barrier #1

  // ---- head loop: {softmax_h} bar {PV_h + K/sel_{h+1}} bar ----
  #pragma unroll
  for (int h = 0; h < 4; ++h){
    float pb[15]; float inv;
    const int bq = lane >> 2, l = lane & 3;
    {
      const int qrow = w*16 + bq;
      short8 sl8 = *(const short8*)(lds + P2o + qrow*64 + l*16);
      float sf[8];
      #pragma unroll
      for (int x = 0; x < 8; ++x) sf[x] = bf2f(sl8[x]);
      #pragma unroll
      for (int j = 0; j < 15; ++j){
        short8 k8 = *(const short8*)(lds + P1o + (j*16 + bq)*64 + l*16);
        float d = 0.f;
        #pragma unroll
        for (int x = 0; x < 8; ++x) d += bf2f(k8[x]) * sf[x];
        d += __shfl_xor(d, 1);
        d += __shfl_xor(d, 2);
        pb[j] = d * 0.17677669529663687f;
      }
      float mx = -1e30f;
      #pragma unroll
      for (int j = 0; j < 15; ++j) if (j != w) mx = fmaxf(mx, pb[j]);
      float sum = 0.f;
      #pragma unroll
      for (int j = 0; j < 15; ++j){
        float p = (j == w) ? 0.f : __expf(pb[j] - mx);
        pb[j] = p; sum += p;
      }
      inv = 1.f / sum;
    }
    __syncthreads();                                       // P1/P2 reads done everywhere

    // next-head K/sel (MFMA, from regs) — overlaps with PV (VALU)
    if (h < 3){
      #pragma unroll
      for (int fn = 0; fn < 2; ++fn){
        int col = fn*16 + l15;
        f32x4 a = (f32x4)0.f, s = (f32x4)0.f;
        const u16* Wkn = WkB   + (size_t)((h+1)*32 + col)*128;
        const u16* Wsn = WselB + (size_t)((h+1)*32 + col)*128;
        #pragma unroll
        for (int ks = 0; ks < 4; ++ks){
          a = MFMA(saA[ks], *(const short8*)(Wkn + ks*32 + l4*8), a);
          s = MFMA(seA[ks], *(const short8*)(Wsn + ks*32 + l4*8), s);
        }
        #pragma unroll
        for (int q = 0; q < 4; ++q){
          int row = w*16 + l4*4 + q;
          *(u16*)(lds + P1o + row*64 + col*2) = f2bf(a[q]);
          *(u16*)(lds + P2o + row*64 + col*2) = f2bf(s[q]);
        }
      }
    }
    // PV: attn_h rows of own agent -> R2 cols h*32..h*32+31
    {
      float oa[8];
      #pragma unroll
      for (int x = 0; x < 8; ++x) oa[x] = 0.f;
      #pragma unroll
      for (int j = 0; j < 15; ++j){
        if (j == w) continue;
        float p = pb[j];
        int row = j*16 + bq;
        short8 v8 = *(const short8*)(lds + R1o + row*256 + (((h*4 + l) ^ (row&7)) << 4));
        #pragma unroll
        for (int x = 0; x < 8; ++x) oa[x] += p * bf2f(v8[x]);
      }
      int row = w*16 + bq;
      short8 o;
      #pragma unroll
      for (int x = 0; x < 8; ++x) o[x] = (short)f2bf(oa[x] * inv);
      *(short8*)(lds + R2o + row*256 + (((h*4 + l) ^ (row&7)) << 4)) = o;
    }
    if (h < 3) __syncthreads();                            // K_{h+1} visible for next softmax
  }

  // ---- critic GEMM1 (single phase): c1 = [SE | attn] @ Wc1, K=256 ----
  short8 at8[4];
  #pragma unroll
  for (int ks = 0; ks < 4; ++ks) at8[ks] = ldA(lds, R2o, w*16 + l15, ks*4 + l4);  // attn frags (own rows)
  {
    const u16* Wc = Wc1B + (size_t)w*32768;
    #pragma unroll
    for (int fn = 0; fn < 8; ++fn){
      int col = fn*16 + l15;
      const u16* Wn = Wc + (size_t)col*256;
      f32x4 a = (f32x4)0.f;
      #pragma unroll
      for (int ks = 0; ks < 4; ++ks) a = MFMA(seA[ks], *(const short8*)(Wn + ks*32 + l4*8), a);
      #pragma unroll
      for (int ks = 0; ks < 4; ++ks) a = MFMA(at8[ks], *(const short8*)(Wn + 128 + ks*32 + l4*8), a);
      float bb = bc1[w*128 + col];
      #pragma unroll
      for (int q = 0; q < 4; ++q){
        int row = w*16 + l4*4 + q;
        float v = a[q] + bb; v = v > 0.f ? v : 0.01f*v;
        stSwz(lds, R2o, row, col, f2bf(v));               // hidden over attn (own rows)
      }
    }
  }
  // ---- GEMM2: out = h @ Wc2 + bc2 (own rows; bounce in P1 region, own 2KB) ----
  short8 h8[4];
  #pragma unroll
  for (int ks = 0; ks < 4; ++ks) h8[ks] = ldA(lds, R2o, w*16 + l15, ks*4 + l4);
  #pragma unroll
  for (int fn = 0; fn < 2; ++fn){
    int col = fn*16 + l15;
    const u16* Wn = Wc2B + (size_t)w*4096 + (size_t)col*128;
    f32x4 a = (f32x4)0.f;
    #pragma unroll
    for (int ks = 0; ks < 4; ++ks) a = MFMA(h8[ks], *(const short8*)(Wn + ks*32 + l4*8), a);
    float bb = bc2[w*32 + col];
    #pragma unroll
    for (int q = 0; q < 4; ++q)
      *(float*)(lds + P1o + w*2048 + (l4*4 + q)*128 + col*4) = a[q] + bb;
  }
  // coalesced copy out (own 2KB, same-wave)
  {
    const char* src = lds + P1o + w*2048 + lane*32;
    float4 o0 = *(const float4*)src, o1 = *(const float4*)(src + 16);
    float* dst = outp + ((size_t)w*NB + b0 + (lane >> 2))*32 + (lane & 3)*8;
    *(float4*)dst = o0; *(float4*)(dst + 4) = o1;
  }
}

// ---------------- launch ----------------
extern "C" void kernel_launch(void* const* d_in, const int* in_sizes, int n_in,
                              void* d_out, int out_size, void* d_ws, size_t ws_size,
                              hipStream_t stream)
{
  const float* states  = (const float*)d_in[0];
  const float* actions = (const float*)d_in[1];
  const float* Wenc    = (const float*)d_in[2];
  const float* benc    = (const float*)d_in[3];
  const float* Wsenc   = (const float*)d_in[4];
  const float* bsenc   = (const float*)d_in[5];
  const float* Wk      = (const float*)d_in[6];
  const float* Wsel    = (const float*)d_in[7];
  const float* Wv      = (const float*)d_in[8];
  const float* bv      = (const float*)d_in[9];
  const float* Wc1     = (const float*)d_in[10];
  const float* bc1     = (const float*)d_in[11];
  const float* Wc2     = (const float*)d_in[12];
  const float* bc2     = (const float*)d_in[13];

  char* ws = (char*)d_ws;
  u16* WencB  = (u16*)(ws + 0);
  u16* WsencB = (u16*)(ws + 614400);
  u16* WkB    = (u16*)(ws + 1105920);
  u16* WvB    = (u16*)(ws + 1138688);
  u16* WselB  = (u16*)(ws + 1171456);
  u16* Wc1B   = (u16*)(ws + 1204224);
  u16* Wc2B   = (u16*)(ws + 2187264);
  if (ws_size < 2310144ULL) return;

  hipFuncSetAttribute((const void*)k_fused, hipFuncAttributeMaxDynamicSharedMemorySize, LDS_TOT);

  k0_conv<<<4512, 256, 0, stream>>>(Wenc, Wsenc, Wk, Wsel, Wv, Wc1, Wc2,
                                    WencB, WsencB, WkB, WvB, WselB, Wc1B, Wc2B);
  k_fused<<<2048, 960, LDS_TOT, stream>>>(states, actions, benc, bsenc, bv, bc1, bc2,
                                          WencB, WsencB, WkB, WvB, WselB, Wc1B, Wc2B,
                                          (float*)d_out);
}

// Round 5
// 976.079 us; speedup vs baseline: 1.0047x; 1.0047x over previous
//
#include <hip/hip_runtime.h>

typedef unsigned short u16;
typedef __attribute__((ext_vector_type(8))) short short8;
typedef __attribute__((ext_vector_type(4))) float f32x4;

#define NB 32768

__device__ __forceinline__ u16 f2bf(float x){
  unsigned int u = __float_as_uint(x);
  u += 0x7fffu + ((u >> 16) & 1u);
  return (u16)(u >> 16);
}
__device__ __forceinline__ float bf2f(short h){
  return __uint_as_float(((unsigned int)(u16)h) << 16);
}
__device__ __forceinline__ short8 pack8(float4 a, float4 b){
  short8 p;
  p[0]=(short)f2bf(a.x); p[1]=(short)f2bf(a.y); p[2]=(short)f2bf(a.z); p[3]=(short)f2bf(a.w);
  p[4]=(short)f2bf(b.x); p[5]=(short)f2bf(b.y); p[6]=(short)f2bf(b.z); p[7]=(short)f2bf(b.w);
  return p;
}

// ---------------- K0: weight convert/transpose to bf16 [N][K] ----------------
__global__ __launch_bounds__(256) void k0_conv(
    const float* __restrict__ Wenc, const float* __restrict__ Wsenc,
    const float* __restrict__ Wk, const float* __restrict__ Wsel, const float* __restrict__ Wv,
    const float* __restrict__ Wc1, const float* __restrict__ Wc2,
    u16* __restrict__ WencB, u16* __restrict__ WsencB,
    u16* __restrict__ WkB, u16* __restrict__ WvB, u16* __restrict__ WselB,
    u16* __restrict__ Wc1B, u16* __restrict__ Wc2B)
{
  int idx = blockIdx.x * 256 + threadIdx.x;
  if (idx < 307200){                       // WencB[a][n<128][k<160] = Wenc[a][k][n]
    int a = idx / 20480, r = idx % 20480, n = r / 160, k = r % 160;
    WencB[idx] = f2bf(Wenc[a*20480 + k*128 + n]);
  } else if (idx < 552960){                // WsencB[a][n][k] 128x128
    int i = idx - 307200; int a = i / 16384, r = i % 16384, n = r / 128, k = r % 128;
    WsencB[i] = f2bf(Wsenc[a*16384 + k*128 + n]);
  } else if (idx < 569344){                // WkB[c=nh*32+d][k<128] = Wk[nh][k][d]
    int i = idx - 552960; int c = i / 128, k = i % 128;
    WkB[i] = f2bf(Wk[(c>>5)*4096 + k*32 + (c&31)]);
  } else if (idx < 585728){
    int i = idx - 569344; int c = i / 128, k = i % 128;
    WvB[i] = f2bf(Wv[(c>>5)*4096 + k*32 + (c&31)]);
  } else if (idx < 602112){
    int i = idx - 585728; int c = i / 128, k = i % 128;
    WselB[i] = f2bf(Wsel[(c>>5)*4096 + k*32 + (c&31)]);
  } else if (idx < 1093632){               // Wc1B[a][n<128][k<256] = Wc1[a][k][n]
    int i = idx - 602112; int a = i / 32768, r = i % 32768, n = r / 256, k = r % 256;
    Wc1B[i] = f2bf(Wc1[a*32768 + k*128 + n]);
  } else if (idx < 1155072){               // Wc2B[a][n<32][k<128] = Wc2[a][k][n]
    int i = idx - 1093632; int a = i / 4096, r = i % 4096, n = r / 128, k = r % 128;
    Wc2B[i] = f2bf(Wc2[a*4096 + k*32 + n]);
  }
}

// ---------------- fused main kernel ----------------
// Block = 16 batch rows x 15 agents; 960 threads = 15 waves; wave w owns agent w.
// LDS:
//   R1 @0      : 61440  SA (own-wave bounce) -> V_all -> attn (per-head col-slot overwrite)
//   R2 @61440  : 61440  SE (lives until critic) -> hidden (own-row overwrite)
//   P1 @122880 : 15360  K_h [240 rows][64B]
//   P2 @138240 : 15360  sel_h [240 rows][64B]      (P1+P2 reused as f32 out bounce at end)
#define R1o 0
#define R2o 61440
#define P1o 122880
#define P2o 138240
#define LDS_TOT 153600

__device__ __forceinline__ short8 ldA(const char* lds, int off, int row, int slot){
  return *(const short8*)(lds + off + row*256 + ((slot ^ (row & 7)) << 4));
}
__device__ __forceinline__ void stSwz(char* lds, int off, int row, int col, u16 v){
  *(u16*)(lds + off + row*256 + ((((col>>3) ^ (row&7))) << 4) + ((col&7) << 1)) = v;
}

#define MFMA(a8,b8,c) __builtin_amdgcn_mfma_f32_16x16x32_bf16(a8, b8, c, 0, 0, 0)

__global__ __launch_bounds__(960, 4) void k_fused(
    const float* __restrict__ states, const float* __restrict__ actions,
    const float* __restrict__ benc, const float* __restrict__ bsenc, const float* __restrict__ bvp,
    const float* __restrict__ bc1, const float* __restrict__ bc2,
    const u16* __restrict__ WencB, const u16* __restrict__ WsencB,
    const u16* __restrict__ WkB, const u16* __restrict__ WvB, const u16* __restrict__ WselB,
    const u16* __restrict__ Wc1B, const u16* __restrict__ Wc2B,
    float* __restrict__ outp)
{
  extern __shared__ __align__(16) char lds[];
  const int b0 = blockIdx.x * 16;
  const int lane = threadIdx.x & 63, w = threadIdx.x >> 6;   // w = agent, 0..14
  const int l15 = lane & 15, l4 = lane >> 4;

  // ---- A-frags of states/actions DIRECT from global (row=l15, k=ks*32+l4*8) ----
  short8 s8[4];
  #pragma unroll
  for (int ks = 0; ks < 4; ++ks){
    const float* sp = states + ((size_t)w*NB + b0 + l15)*128 + ks*32 + l4*8;
    float4 v0 = *(const float4*)sp, v1 = *(const float4*)(sp + 4);
    s8[ks] = pack8(v0, v1);
  }
  short8 aa;
  {
    const float* ap = actions + ((size_t)w*NB + b0 + l15)*32 + l4*8;
    float4 v0 = *(const float4*)ap, v1 = *(const float4*)(ap + 4);
    aa = pack8(v0, v1);
  }

  // ---- SA = lrelu([S|act] @ Wenc + benc) -> R1 own rows (bounce) ----
  {
    const u16* We = WencB + (size_t)w*20480;
    #pragma unroll
    for (int c = 0; c < 8; ++c){
      int col = c*16 + l15;
      const u16* Wn = We + (size_t)col*160;
      f32x4 a = (f32x4)0.f;
      #pragma unroll
      for (int ks = 0; ks < 4; ++ks) a = MFMA(s8[ks], *(const short8*)(Wn + ks*32 + l4*8), a);
      a = MFMA(aa, *(const short8*)(Wn + 128 + l4*8), a);
      float bb = benc[w*128 + col];
      #pragma unroll
      for (int q = 0; q < 4; ++q){
        int row = w*16 + l4*4 + q;
        float v = a[q] + bb; v = v > 0.f ? v : 0.01f*v;
        stSwz(lds, R1o, row, col, f2bf(v));
      }
    }
  }
  // persistent SA A-frags (only cross-phase register state in the kernel)
  short8 saA[4];
  #pragma unroll
  for (int ks = 0; ks < 4; ++ks) saA[ks] = ldA(lds, R1o, w*16 + l15, ks*4 + l4);

  // ---- SE = lrelu(S @ Wsenc + bsenc) -> R2 own rows (stays live until critic) ----
  {
    const u16* Ws = WsencB + (size_t)w*16384;
    #pragma unroll
    for (int c = 0; c < 8; ++c){
      int col = c*16 + l15;
      const u16* Wn = Ws + (size_t)col*128;
      f32x4 a = (f32x4)0.f;
      #pragma unroll
      for (int ks = 0; ks < 4; ++ks) a = MFMA(s8[ks], *(const short8*)(Wn + ks*32 + l4*8), a);
      float bb = bsenc[w*128 + col];
      #pragma unroll
      for (int q = 0; q < 4; ++q){
        int row = w*16 + l4*4 + q;
        float v = a[q] + bb; v = v > 0.f ? v : 0.01f*v;
        stSwz(lds, R2o, row, col, f2bf(v));
      }
    }
  }

  // ---- V_all = lrelu(SA @ Wv + bv) -> R1 own rows (overwrites SA bounce) ----
  #pragma unroll
  for (int c = 0; c < 8; ++c){
    int col = c*16 + l15;                       // col = h*32 + d
    const u16* Wn = WvB + (size_t)col*128;
    f32x4 a = (f32x4)0.f;
    #pragma unroll
    for (int ks = 0; ks < 4; ++ks) a = MFMA(saA[ks], *(const short8*)(Wn + ks*32 + l4*8), a);
    float bb = bvp[col];
    #pragma unroll
    for (int q = 0; q < 4; ++q){
      int row = w*16 + l4*4 + q;
      float v = a[q] + bb; v = v > 0.f ? v : 0.01f*v;
      stSwz(lds, R1o, row, col, f2bf(v));
    }
  }
  // ---- K_0 -> P1, sel_0 -> P2 (seA read transiently from R2) ----
  {
    short8 se2[4];
    #pragma unroll
    for (int ks = 0; ks < 4; ++ks) se2[ks] = ldA(lds, R2o, w*16 + l15, ks*4 + l4);
    #pragma unroll
    for (int fn = 0; fn < 2; ++fn){
      int col = fn*16 + l15;
      f32x4 kk = (f32x4)0.f, ss = (f32x4)0.f;
      const u16* Wkn = WkB   + (size_t)col*128;
      const u16* Wsn = WselB + (size_t)col*128;
      #pragma unroll
      for (int ks = 0; ks < 4; ++ks){
        kk = MFMA(saA[ks], *(const short8*)(Wkn + ks*32 + l4*8), kk);
        ss = MFMA(se2[ks], *(const short8*)(Wsn + ks*32 + l4*8), ss);
      }
      #pragma unroll
      for (int q = 0; q < 4; ++q){
        int row = w*16 + l4*4 + q;
        *(u16*)(lds + P1o + row*64 + col*2) = f2bf(kk[q]);
        *(u16*)(lds + P2o + row*64 + col*2) = f2bf(ss[q]);
      }
    }
  }
  __syncthreads();                               // barrier 1: K_0/sel_0/V_all/SE visible

  // ---- head loop ----
  const int bq = lane >> 2, l = lane & 3;
  for (int h = 0; h < 4; ++h){
    // phase A: softmax + PV (pure reads of P1/P2/R1)
    short8 o;
    {
      const int qrow = w*16 + bq;
      short8 sl8 = *(const short8*)(lds + P2o + qrow*64 + l*16);
      float sf[8];
      #pragma unroll
      for (int x = 0; x < 8; ++x) sf[x] = bf2f(sl8[x]);
      float pb[15];
      #pragma unroll
      for (int j = 0; j < 15; ++j){
        short8 k8 = *(const short8*)(lds + P1o + (j*16 + bq)*64 + l*16);
        float d = 0.f;
        #pragma unroll
        for (int x = 0; x < 8; ++x) d += bf2f(k8[x]) * sf[x];
        d += __shfl_xor(d, 1);
        d += __shfl_xor(d, 2);
        pb[j] = d * 0.17677669529663687f;
      }
      float mx = -1e30f;
      #pragma unroll
      for (int j = 0; j < 15; ++j) if (j != w) mx = fmaxf(mx, pb[j]);
      float sum = 0.f;
      #pragma unroll
      for (int j = 0; j < 15; ++j){
        float p = (j == w) ? 0.f : __expf(pb[j] - mx);
        pb[j] = p; sum += p;
      }
      float inv = 1.f / sum;
      float oa[8];
      #pragma unroll
      for (int x = 0; x < 8; ++x) oa[x] = 0.f;
      #pragma unroll
      for (int j = 0; j < 15; ++j){
        if (j == w) continue;
        float p = pb[j];
        int row = j*16 + bq;
        short8 v8 = *(const short8*)(lds + R1o + row*256 + (((h*4 + l) ^ (row&7)) << 4));
        #pragma unroll
        for (int x = 0; x < 8; ++x) oa[x] += p * bf2f(v8[x]);
      }
      #pragma unroll
      for (int x = 0; x < 8; ++x) o[x] = (short)f2bf(oa[x] * inv);
    }
    __syncthreads();                             // all reads of V_h/K_h/sel_h done

    // phase B: attn_h -> R1 over V_h cols (own rows); K/sel_{h+1} -> P1/P2 (own rows)
    {
      int row = w*16 + bq;
      *(short8*)(lds + R1o + row*256 + (((h*4 + l) ^ (row&7)) << 4)) = o;
    }
    if (h < 3){
      short8 se2[4];
      #pragma unroll
      for (int ks = 0; ks < 4; ++ks) se2[ks] = ldA(lds, R2o, w*16 + l15, ks*4 + l4);
      #pragma unroll
      for (int fn = 0; fn < 2; ++fn){
        int col = fn*16 + l15;
        f32x4 kk = (f32x4)0.f, ss = (f32x4)0.f;
        const u16* Wkn = WkB   + (size_t)((h+1)*32 + col)*128;
        const u16* Wsn = WselB + (size_t)((h+1)*32 + col)*128;
        #pragma unroll
        for (int ks = 0; ks < 4; ++ks){
          kk = MFMA(saA[ks], *(const short8*)(Wkn + ks*32 + l4*8), kk);
          ss = MFMA(se2[ks], *(const short8*)(Wsn + ks*32 + l4*8), ss);
        }
        #pragma unroll
        for (int q = 0; q < 4; ++q){
          int row = w*16 + l4*4 + q;
          *(u16*)(lds + P1o + row*64 + col*2) = f2bf(kk[q]);
          *(u16*)(lds + P2o + row*64 + col*2) = f2bf(ss[q]);
        }
      }
      __syncthreads();                           // K/sel_{h+1} + attn_h visible
    }
  }

  // ---- critic GEMM1: hidden = lrelu([SE | attn] @ Wc1 + bc1), K=256 (all same-wave reads) ----
  {
    short8 se2[4], at8[4];
    #pragma unroll
    for (int ks = 0; ks < 4; ++ks){
      se2[ks] = ldA(lds, R2o, w*16 + l15, ks*4 + l4);   // SE intact in R2
      at8[ks] = ldA(lds, R1o, w*16 + l15, ks*4 + l4);   // attn (own rows, own-wave written)
    }
    const u16* Wc = Wc1B + (size_t)w*32768;
    #pragma unroll
    for (int fn = 0; fn < 8; ++fn){
      int col = fn*16 + l15;
      const u16* Wn = Wc + (size_t)col*256;
      f32x4 a = (f32x4)0.f;
      #pragma unroll
      for (int ks = 0; ks < 4; ++ks) a = MFMA(se2[ks], *(const short8*)(Wn + ks*32 + l4*8), a);
      #pragma unroll
      for (int ks = 0; ks < 4; ++ks) a = MFMA(at8[ks], *(const short8*)(Wn + 128 + ks*32 + l4*8), a);
      float bb = bc1[w*128 + col];
      #pragma unroll
      for (int q = 0; q < 4; ++q){
        int row = w*16 + l4*4 + q;
        float v = a[q] + bb; v = v > 0.f ? v : 0.01f*v;
        stSwz(lds, R2o, row, col, f2bf(v));             // hidden over SE (own rows)
      }
    }
  }
  // ---- GEMM2: out = hidden @ Wc2 + bc2 (own rows; f32 bounce in P region) ----
  {
    short8 h8[4];
    #pragma unroll
    for (int ks = 0; ks < 4; ++ks) h8[ks] = ldA(lds, R2o, w*16 + l15, ks*4 + l4);
    #pragma unroll
    for (int fn = 0; fn < 2; ++fn){
      int col = fn*16 + l15;
      const u16* Wn = Wc2B + (size_t)w*4096 + (size_t)col*128;
      f32x4 a = (f32x4)0.f;
      #pragma unroll
      for (int ks = 0; ks < 4; ++ks) a = MFMA(h8[ks], *(const short8*)(Wn + ks*32 + l4*8), a);
      float bb = bc2[w*32 + col];
      #pragma unroll
      for (int q = 0; q < 4; ++q)
        *(float*)(lds + P1o + w*2048 + (l4*4 + q)*128 + col*4) = a[q] + bb;
    }
    const char* src = lds + P1o + w*2048 + lane*32;
    float4 o0 = *(const float4*)src, o1 = *(const float4*)(src + 16);
    float* dst = outp + ((size_t)w*NB + b0 + (lane >> 2))*32 + (lane & 3)*8;
    *(float4*)dst = o0; *(float4*)(dst + 4) = o1;
  }
}

// ---------------- launch ----------------
extern "C" void kernel_launch(void* const* d_in, const int* in_sizes, int n_in,
                              void* d_out, int out_size, void* d_ws, size_t ws_size,
                              hipStream_t stream)
{
  const float* states  = (const float*)d_in[0];
  const float* actions = (const float*)d_in[1];
  const float* Wenc    = (const float*)d_in[2];
  const float* benc    = (const float*)d_in[3];
  const float* Wsenc   = (const float*)d_in[4];
  const float* bsenc   = (const float*)d_in[5];
  const float* Wk      = (const float*)d_in[6];
  const float* Wsel    = (const float*)d_in[7];
  const float* Wv      = (const float*)d_in[8];
  const float* bv      = (const float*)d_in[9];
  const float* Wc1     = (const float*)d_in[10];
  const float* bc1     = (const float*)d_in[11];
  const float* Wc2     = (const float*)d_in[12];
  const float* bc2     = (const float*)d_in[13];

  char* ws = (char*)d_ws;
  u16* WencB  = (u16*)(ws + 0);
  u16* WsencB = (u16*)(ws + 614400);
  u16* WkB    = (u16*)(ws + 1105920);
  u16* WvB    = (u16*)(ws + 1138688);
  u16* WselB  = (u16*)(ws + 1171456);
  u16* Wc1B   = (u16*)(ws + 1204224);
  u16* Wc2B   = (u16*)(ws + 2187264);
  if (ws_size < 2310144ULL) return;

  hipFuncSetAttribute((const void*)k_fused, hipFuncAttributeMaxDynamicSharedMemorySize, LDS_TOT);

  k0_conv<<<4512, 256, 0, stream>>>(Wenc, Wsenc, Wk, Wsel, Wv, Wc1, Wc2,
                                    WencB, WsencB, WkB, WvB, WselB, Wc1B, Wc2B);
  k_fused<<<2048, 960, LDS_TOT, stream>>>(states, actions, benc, bsenc, bv, bc1, bc2,
                                          WencB, WsencB, WkB, WvB, WselB, Wc1B, Wc2B,
                                          (float*)d_out);
}

// Round 6
// 855.285 us; speedup vs baseline: 1.1466x; 1.1412x over previous
//
#include <hip/hip_runtime.h>

typedef unsigned short u16;
typedef __attribute__((ext_vector_type(8))) short short8;
typedef __attribute__((ext_vector_type(4))) float f32x4;

#define NB 32768

__device__ __forceinline__ u16 f2bf(float x){
  unsigned int u = __float_as_uint(x);
  u += 0x7fffu + ((u >> 16) & 1u);
  return (u16)(u >> 16);
}
__device__ __forceinline__ float bf2f(short h){
  return __uint_as_float(((unsigned int)(u16)h) << 16);
}
__device__ __forceinline__ short8 pack8(float4 a, float4 b){
  short8 p;
  p[0]=(short)f2bf(a.x); p[1]=(short)f2bf(a.y); p[2]=(short)f2bf(a.z); p[3]=(short)f2bf(a.w);
  p[4]=(short)f2bf(b.x); p[5]=(short)f2bf(b.y); p[6]=(short)f2bf(b.z); p[7]=(short)f2bf(b.w);
  return p;
}

// ---------------- K0: weight convert/transpose to bf16 [N][K] ----------------
__global__ __launch_bounds__(256) void k0_conv(
    const float* __restrict__ Wenc, const float* __restrict__ Wsenc,
    const float* __restrict__ Wk, const float* __restrict__ Wsel, const float* __restrict__ Wv,
    const float* __restrict__ Wc1, const float* __restrict__ Wc2,
    u16* __restrict__ WencB, u16* __restrict__ WsencB,
    u16* __restrict__ WkB, u16* __restrict__ WvB, u16* __restrict__ WselB,
    u16* __restrict__ Wc1B, u16* __restrict__ Wc2B)
{
  int idx = blockIdx.x * 256 + threadIdx.x;
  if (idx < 307200){                       // WencB[a][n<128][k<160] = Wenc[a][k][n]
    int a = idx / 20480, r = idx % 20480, n = r / 160, k = r % 160;
    WencB[idx] = f2bf(Wenc[a*20480 + k*128 + n]);
  } else if (idx < 552960){                // WsencB[a][n][k] 128x128
    int i = idx - 307200; int a = i / 16384, r = i % 16384, n = r / 128, k = r % 128;
    WsencB[i] = f2bf(Wsenc[a*16384 + k*128 + n]);
  } else if (idx < 569344){                // WkB[c=nh*32+d][k<128] = Wk[nh][k][d]
    int i = idx - 552960; int c = i / 128, k = i % 128;
    WkB[i] = f2bf(Wk[(c>>5)*4096 + k*32 + (c&31)]);
  } else if (idx < 585728){
    int i = idx - 569344; int c = i / 128, k = i % 128;
    WvB[i] = f2bf(Wv[(c>>5)*4096 + k*32 + (c&31)]);
  } else if (idx < 602112){
    int i = idx - 585728; int c = i / 128, k = i % 128;
    WselB[i] = f2bf(Wsel[(c>>5)*4096 + k*32 + (c&31)]);
  } else if (idx < 1093632){               // Wc1B[a][n<128][k<256] = Wc1[a][k][n]
    int i = idx - 602112; int a = i / 32768, r = i % 32768, n = r / 256, k = r % 256;
    Wc1B[i] = f2bf(Wc1[a*32768 + k*128 + n]);
  } else if (idx < 1155072){               // Wc2B[a][n<32][k<128] = Wc2[a][k][n]
    int i = idx - 1093632; int a = i / 4096, r = i % 4096, n = r / 128, k = r % 128;
    Wc2B[i] = f2bf(Wc2[a*4096 + k*32 + n]);
  }
}

// ---------------- helpers ----------------
__device__ __forceinline__ short8 ldA(const char* lds, int off, int row, int slot){
  return *(const short8*)(lds + off + row*256 + ((slot ^ (row & 7)) << 4));
}
__device__ __forceinline__ void stSwz(char* lds, int off, int row, int col, u16 v){
  *(u16*)(lds + off + row*256 + ((((col>>3) ^ (row&7))) << 4) + ((col&7) << 1)) = v;
}
#define MFMA(a8,b8,c) __builtin_amdgcn_mfma_f32_16x16x32_bf16(a8, b8, c, 0, 0, 0)

// ---------------- K1: encoders + projections (no barriers, wave-independent) ----------------
// grid (256, 15), block 256 thr = 4 waves; wave owns 32 rows (2 MFMA row-sets sharing B-frags).
// LDS: per-wave 8 KB bounce [32 rows][256B] swizzled.
__device__ __forceinline__ void k1_gemm128(
    char* B, const short8* A0, const short8* A1, const u16* __restrict__ W,
    const float* __restrict__ bias, bool act, int l15, int l4)
{
  #pragma unroll
  for (int c = 0; c < 8; ++c){
    int col = c*16 + l15;
    const u16* Wn = W + (size_t)col*128;
    f32x4 a0 = (f32x4)0.f, a1 = (f32x4)0.f;
    #pragma unroll
    for (int ks = 0; ks < 4; ++ks){
      short8 b8 = *(const short8*)(Wn + ks*32 + l4*8);
      a0 = MFMA(A0[ks], b8, a0);
      a1 = MFMA(A1[ks], b8, a1);
    }
    float bb = bias ? bias[col] : 0.0f;
    #pragma unroll
    for (int q = 0; q < 4; ++q){
      float v0 = a0[q] + bb, v1 = a1[q] + bb;
      if (act){ v0 = v0 > 0.f ? v0 : 0.01f*v0; v1 = v1 > 0.f ? v1 : 0.01f*v1; }
      stSwz(B, 0, l4*4 + q,      col, f2bf(v0));
      stSwz(B, 0, 16 + l4*4 + q, col, f2bf(v1));
    }
  }
}
__device__ __forceinline__ void k1_copyout(const char* B, u16* __restrict__ dst,
                                           int a, int m0, int lane)
{
  #pragma unroll
  for (int it = 0; it < 8; ++it){
    int e = lane + it*64, row = e >> 4, cb = e & 15;
    *(short8*)(dst + ((size_t)a*NB + m0 + row)*128 + cb*8) =
        *(const short8*)(B + row*256 + ((cb ^ (row&7)) << 4));
  }
}

__global__ __launch_bounds__(256, 4) void k1_enc(
    const float* __restrict__ states, const float* __restrict__ actions,
    const float* __restrict__ benc, const float* __restrict__ bsenc, const float* __restrict__ bvp,
    const u16* __restrict__ WencB, const u16* __restrict__ WsencB,
    const u16* __restrict__ WkB, const u16* __restrict__ WvB, const u16* __restrict__ WselB,
    u16* __restrict__ senc_g, u16* __restrict__ keys_g, u16* __restrict__ vals_g, u16* __restrict__ sel_g)
{
  extern __shared__ __align__(16) char lds[];
  const int a = blockIdx.y;
  const int w = threadIdx.x >> 6, lane = threadIdx.x & 63;
  const int l15 = lane & 15, l4 = lane >> 4;
  const int m0 = blockIdx.x*128 + w*32;
  char* B = lds + w*8192;

  // states/actions A-frags direct from global (two row-sets)
  short8 s0[4], s1[4], aa0, aa1;
  #pragma unroll
  for (int ks = 0; ks < 4; ++ks){
    const float* p0 = states + ((size_t)a*NB + m0 + l15)*128 + ks*32 + l4*8;
    s0[ks] = pack8(*(const float4*)p0, *(const float4*)(p0 + 4));
    const float* p1 = p0 + 16*128;
    s1[ks] = pack8(*(const float4*)p1, *(const float4*)(p1 + 4));
  }
  {
    const float* q0 = actions + ((size_t)a*NB + m0 + l15)*32 + l4*8;
    aa0 = pack8(*(const float4*)q0, *(const float4*)(q0 + 4));
    const float* q1 = q0 + 16*32;
    aa1 = pack8(*(const float4*)q1, *(const float4*)(q1 + 4));
  }

  // ---- SA = lrelu([S|act] @ Wenc + benc) -> bounce ----
  {
    const u16* We = WencB + (size_t)a*20480;
    const float* bi = benc + a*128;
    #pragma unroll
    for (int c = 0; c < 8; ++c){
      int col = c*16 + l15;
      const u16* Wn = We + (size_t)col*160;
      f32x4 a0 = (f32x4)0.f, a1 = (f32x4)0.f;
      #pragma unroll
      for (int ks = 0; ks < 4; ++ks){
        short8 b8 = *(const short8*)(Wn + ks*32 + l4*8);
        a0 = MFMA(s0[ks], b8, a0);
        a1 = MFMA(s1[ks], b8, a1);
      }
      short8 bt = *(const short8*)(Wn + 128 + l4*8);
      a0 = MFMA(aa0, bt, a0);
      a1 = MFMA(aa1, bt, a1);
      float bb = bi[col];
      #pragma unroll
      for (int q = 0; q < 4; ++q){
        float v0 = a0[q] + bb, v1 = a1[q] + bb;
        v0 = v0 > 0.f ? v0 : 0.01f*v0; v1 = v1 > 0.f ? v1 : 0.01f*v1;
        stSwz(B, 0, l4*4 + q,      col, f2bf(v0));
        stSwz(B, 0, 16 + l4*4 + q, col, f2bf(v1));
      }
    }
  }
  short8 saA0[4], saA1[4];
  #pragma unroll
  for (int ks = 0; ks < 4; ++ks){
    saA0[ks] = ldA(B, 0, l15,      ks*4 + l4);
    saA1[ks] = ldA(B, 0, 16 + l15, ks*4 + l4);
  }

  // ---- SE = lrelu(S @ Wsenc + bsenc) -> bounce -> senc out + seA frags ----
  k1_gemm128(B, s0, s1, WsencB + (size_t)a*16384, bsenc + a*128, true, l15, l4);
  k1_copyout(B, senc_g, a, m0, lane);
  short8 seA0[4], seA1[4];
  #pragma unroll
  for (int ks = 0; ks < 4; ++ks){
    seA0[ks] = ldA(B, 0, l15,      ks*4 + l4);
    seA1[ks] = ldA(B, 0, 16 + l15, ks*4 + l4);
  }

  // ---- keys = SA @ Wk ----
  k1_gemm128(B, saA0, saA1, WkB, (const float*)nullptr, false, l15, l4);
  k1_copyout(B, keys_g, a, m0, lane);
  // ---- vals = lrelu(SA @ Wv + bv) ----
  k1_gemm128(B, saA0, saA1, WvB, bvp, true, l15, l4);
  k1_copyout(B, vals_g, a, m0, lane);
  // ---- sel = SE @ Wsel ----
  k1_gemm128(B, seA0, seA1, WselB, (const float*)nullptr, false, l15, l4);
  k1_copyout(B, sel_g, a, m0, lane);
}

// ---------------- K2: attention + critic ----------------
// block = 16 batch rows x 15 agents, 960 thr = 15 waves (wave w = agent w).
// LDS: K @0 [240][256B swz] 61440; V @61440 same. attn bounces into K region (dead after barrier 2).
#define KO 0
#define VO 61440
#define K2_LDS 122880

__global__ __launch_bounds__(960, 4) void k2_ac(
    const u16* __restrict__ senc_g, const u16* __restrict__ keys_g,
    const u16* __restrict__ vals_g, const u16* __restrict__ sel_g,
    const float* __restrict__ bc1, const float* __restrict__ bc2,
    const u16* __restrict__ Wc1B, const u16* __restrict__ Wc2B,
    float* __restrict__ outp)
{
  extern __shared__ __align__(16) char lds[];
  const int b0 = blockIdx.x * 16;
  const int t = threadIdx.x;
  const int lane = t & 63, w = t >> 6;
  const int l15 = lane & 15, l4 = lane >> 4;

  // ---- stage keys + vals ----
  #pragma unroll
  for (int it = 0; it < 4; ++it){
    int e = t + it*960, row = e >> 4, cb = e & 15;
    size_t src = ((size_t)(row >> 4)*NB + b0 + (row & 15))*128 + cb*8;
    int dst = row*256 + ((cb ^ (row&7)) << 4);
    *(short8*)(lds + KO + dst) = *(const short8*)(keys_g + src);
    *(short8*)(lds + VO + dst) = *(const short8*)(vals_g + src);
  }
  __syncthreads();                                   // barrier 1

  // ---- attention: one thread per (agent w, row b, head h) ----
  const int b = lane >> 2, h = lane & 3;
  float pb[15]; float inv;
  {
    float sf[32];
    size_t sbase = ((size_t)w*NB + b0 + b)*128 + h*32;
    #pragma unroll
    for (int x = 0; x < 4; ++x){
      short8 s8 = *(const short8*)(sel_g + sbase + x*8);
      #pragma unroll
      for (int y = 0; y < 8; ++y) sf[x*8+y] = bf2f(s8[y]);
    }
    #pragma unroll
    for (int j = 0; j < 15; ++j){
      int row = j*16 + b;
      float d = 0.f;
      #pragma unroll
      for (int x = 0; x < 4; ++x){
        short8 k8 = *(const short8*)(lds + KO + row*256 + (((h*4 + x) ^ (row&7)) << 4));
        #pragma unroll
        for (int y = 0; y < 8; ++y) d += bf2f(k8[y]) * sf[x*8+y];
      }
      pb[j] = d * 0.17677669529663687f;              // 1/sqrt(32)
    }
    float mx = -1e30f;
    #pragma unroll
    for (int j = 0; j < 15; ++j) if (j != w) mx = fmaxf(mx, pb[j]);
    float sum = 0.f;
    #pragma unroll
    for (int j = 0; j < 15; ++j){
      float p = (j == w) ? 0.f : __expf(pb[j] - mx);
      pb[j] = p; sum += p;
    }
    inv = 1.f / sum;
  }
  __syncthreads();                                   // barrier 2: K reads done block-wide

  // ---- PV -> attn (bf16) into K region (own rows) ----
  {
    float oa[32];
    #pragma unroll
    for (int x = 0; x < 32; ++x) oa[x] = 0.f;
    #pragma unroll
    for (int j = 0; j < 15; ++j){
      if (j == w) continue;
      float p = pb[j];
      int row = j*16 + b;
      #pragma unroll
      for (int x = 0; x < 4; ++x){
        short8 v8 = *(const short8*)(lds + VO + row*256 + (((h*4 + x) ^ (row&7)) << 4));
        #pragma unroll
        for (int y = 0; y < 8; ++y) oa[x*8+y] += p * bf2f(v8[y]);
      }
    }
    int row = w*16 + b;
    #pragma unroll
    for (int x = 0; x < 4; ++x){
      short8 o;
      #pragma unroll
      for (int y = 0; y < 8; ++y) o[y] = (short)f2bf(oa[x*8+y] * inv);
      *(short8*)(lds + KO + row*256 + (((h*4 + x) ^ (row&7)) << 4)) = o;
    }
  }

  // ---- critic (same-wave reads only; waves run free) ----
  short8 A1[4], A2[4];
  #pragma unroll
  for (int ks = 0; ks < 4; ++ks){
    const u16* sp = senc_g + ((size_t)w*NB + b0 + l15)*128 + ks*32 + l4*8;
    A1[ks] = *(const short8*)sp;
    A2[ks] = ldA(lds, KO, w*16 + l15, ks*4 + l4);
  }
  {
    const u16* Wc = Wc1B + (size_t)w*32768;
    const float* bi = bc1 + w*128;
    #pragma unroll
    for (int fn = 0; fn < 8; ++fn){
      int col = fn*16 + l15;
      const u16* Wn = Wc + (size_t)col*256;
      f32x4 acc = (f32x4)0.f;
      #pragma unroll
      for (int ks = 0; ks < 4; ++ks) acc = MFMA(A1[ks], *(const short8*)(Wn + ks*32 + l4*8), acc);
      #pragma unroll
      for (int ks = 0; ks < 4; ++ks) acc = MFMA(A2[ks], *(const short8*)(Wn + 128 + ks*32 + l4*8), acc);
      float bb = bi[col];
      #pragma unroll
      for (int q = 0; q < 4; ++q){
        int row = w*16 + l4*4 + q;
        float v = acc[q] + bb; v = v > 0.f ? v : 0.01f*v;
        stSwz(lds, KO, row, col, f2bf(v));           // hidden over attn (own rows, A2 already read)
      }
    }
  }
  {
    short8 h8[4];
    #pragma unroll
    for (int ks = 0; ks < 4; ++ks) h8[ks] = ldA(lds, KO, w*16 + l15, ks*4 + l4);
    #pragma unroll
    for (int fn = 0; fn < 2; ++fn){
      int col = fn*16 + l15;
      const u16* Wn = Wc2B + (size_t)w*4096 + (size_t)col*128;
      f32x4 acc = (f32x4)0.f;
      #pragma unroll
      for (int ks = 0; ks < 4; ++ks) acc = MFMA(h8[ks], *(const short8*)(Wn + ks*32 + l4*8), acc);
      float bb = bc2[w*32 + col];
      #pragma unroll
      for (int q = 0; q < 4; ++q){
        int row = l4*4 + q;
        outp[((size_t)w*NB + b0 + row)*32 + col] = acc[q] + bb;
      }
    }
  }
}

// ---------------- launch ----------------
extern "C" void kernel_launch(void* const* d_in, const int* in_sizes, int n_in,
                              void* d_out, int out_size, void* d_ws, size_t ws_size,
                              hipStream_t stream)
{
  const float* states  = (const float*)d_in[0];
  const float* actions = (const float*)d_in[1];
  const float* Wenc    = (const float*)d_in[2];
  const float* benc    = (const float*)d_in[3];
  const float* Wsenc   = (const float*)d_in[4];
  const float* bsenc   = (const float*)d_in[5];
  const float* Wk      = (const float*)d_in[6];
  const float* Wsel    = (const float*)d_in[7];
  const float* Wv      = (const float*)d_in[8];
  const float* bv      = (const float*)d_in[9];
  const float* Wc1     = (const float*)d_in[10];
  const float* bc1     = (const float*)d_in[11];
  const float* Wc2     = (const float*)d_in[12];
  const float* bc2     = (const float*)d_in[13];

  char* ws = (char*)d_ws;
  u16* WencB  = (u16*)(ws + 0);
  u16* WsencB = (u16*)(ws + 614400);
  u16* WkB    = (u16*)(ws + 1105920);
  u16* WvB    = (u16*)(ws + 1138688);
  u16* WselB  = (u16*)(ws + 1171456);
  u16* Wc1B   = (u16*)(ws + 1204224);
  u16* Wc2B   = (u16*)(ws + 2187264);
  u16* senc_g = (u16*)(ws + 2310144);
  u16* keys_g = (u16*)(ws + 128139264);
  u16* vals_g = (u16*)(ws + 253968384);
  u16* sel_g  = (u16*)(ws + 379797504);
  if (ws_size < 505626624ULL) return;

  hipFuncSetAttribute((const void*)k1_enc, hipFuncAttributeMaxDynamicSharedMemorySize, 32768);
  hipFuncSetAttribute((const void*)k2_ac,  hipFuncAttributeMaxDynamicSharedMemorySize, K2_LDS);

  k0_conv<<<4512, 256, 0, stream>>>(Wenc, Wsenc, Wk, Wsel, Wv, Wc1, Wc2,
                                    WencB, WsencB, WkB, WvB, WselB, Wc1B, Wc2B);
  k1_enc<<<dim3(256, 15), 256, 32768, stream>>>(states, actions, benc, bsenc, bv,
                                                WencB, WsencB, WkB, WvB, WselB,
                                                senc_g, keys_g, vals_g, sel_g);
  k2_ac<<<2048, 960, K2_LDS, stream>>>(senc_g, keys_g, vals_g, sel_g,
                                       bc1, bc2, Wc1B, Wc2B, (float*)d_out);
}